// Round 2
// baseline (454.961 us; speedup 1.0000x reference)
//
#include <hip/hip_runtime.h>
#include <math.h>

#define LSEQ 128
#define BB 8
#define M_TOK (BB*LSEQ)   // 1024
#define CONV_BLOCKS 320

typedef __attribute__((ext_vector_type(8))) short short8;
typedef __attribute__((ext_vector_type(4))) float floatx4;

__device__ __forceinline__ unsigned short bf16_rne(float v) {
    union { float f; unsigned u; } a; a.f = v;
    return (unsigned short)((a.u + 0x7fffu + ((a.u >> 16) & 1u)) >> 16);
}
__device__ __forceinline__ float bf16_to_f(unsigned short h) {
    union { unsigned u; float f; } b; b.u = ((unsigned)h) << 16;
    return b.f;
}
__device__ __forceinline__ void split2(float v, unsigned short& h, unsigned short& l) {
    h = bf16_rne(v);
    l = bf16_rne(v - bf16_to_f(h));
}

// software grid barrier: per-phase arrive counter, spin until == nb.
// Counters zeroed by stage_kernel each iteration. Requires all blocks co-resident
// (320 blocks, 33KB LDS, __launch_bounds__(256,2) -> >=2 blocks/CU -> capacity 512).
__device__ __forceinline__ void gbar(int* bars, int phase, int nb) {
    __syncthreads();
    if (threadIdx.x == 0) {
        __threadfence();   // agent-scope release of this block's writes
        __hip_atomic_fetch_add(bars + phase * 64, 1, __ATOMIC_ACQ_REL, __HIP_MEMORY_SCOPE_AGENT);
        while (__hip_atomic_load(bars + phase * 64, __ATOMIC_ACQUIRE, __HIP_MEMORY_SCOPE_AGENT) < nb)
            __builtin_amdgcn_s_sleep(2);
        __threadfence();   // agent-scope acquire before reading others' writes
    }
    __syncthreads();
}

// ---------------- staging: pack all conv weights (split bf16, MFMA B-layout),
// embedding gather+split, Wfc, + zero grid-barrier counters ----------------
struct PreArgs {
    const float *w1, *w2, *w3, *w4, *w5;
    unsigned short *B1h, *B1l, *B2h, *B2l, *B3h, *B3l, *B4h, *B4l, *B5h, *B5l;
    const int* x;
    const float* gen;
    const float* dom;
    unsigned short *Eh, *El;
    const float* wf;
    const float* wc;
    float* Wfc;
    int* bars;
};
__global__ __launch_bounds__(256) void stage_kernel(PreArgs a) {
    int y = blockIdx.y;
    int tid = threadIdx.x;
    if (y < 3) {
        const float* w = (y == 0) ? a.w3 : (y == 1) ? a.w4 : a.w5;
        unsigned short* dh = (y == 0) ? a.B3h : (y == 1) ? a.B4h : a.B5h;
        unsigned short* dl = (y == 0) ? a.B3l : (y == 1) ? a.B4l : a.B5l;
        int idx = blockIdx.x * 256 + tid;          // < 327680 exactly
        int j = idx & 7;
        int n = (idx >> 3) & 255;
        int g = idx >> 11;
        int cg = g & 31, kk = g >> 5;
        int ci = cg * 8 + j;
        float v = w[(n * 256 + ci) * 5 + kk];
        unsigned short h, l; split2(v, h, l);
        dh[idx] = h; dl[idx] = l;
    } else if (y == 3) {
        int idx = blockIdx.x * 256 + tid;
        if (idx >= 5 * 52 * 128 * 8) return;
        int j = idx & 7;
        int n = (idx >> 3) & 127;
        int g = idx >> 10;
        int cg = g % 52, kk = g / 52;
        int ci = cg * 8 + j;
        float v = (ci < 400) ? a.w1[(n * 400 + ci) * 5 + kk] : 0.f;
        unsigned short h, l; split2(v, h, l);
        a.B1h[idx] = h; a.B1l[idx] = l;
    } else if (y == 4) {
        int idx = blockIdx.x * 256 + tid;
        if (idx >= 3 * 52 * 128 * 8) return;
        int j = idx & 7;
        int n = (idx >> 3) & 127;
        int g = idx >> 10;
        int cg = g % 52, kk = g / 52;
        int ci = cg * 8 + j;
        float v = (ci < 400) ? a.w2[(n * 400 + ci) * 3 + kk] : 0.f;
        unsigned short h, l; split2(v, h, l);
        a.B2h[idx] = h; a.B2l[idx] = l;
    } else if (y == 5) {
        int m = blockIdx.x;
        if (m >= M_TOK) return;
        int t = a.x[m];
        for (int c = tid; c < 416; c += 256) {
            float v = (c < 300) ? a.gen[t * 300 + c]
                    : (c < 400) ? a.dom[t * 100 + (c - 300)] : 0.f;
            unsigned short h, l; split2(v, h, l);
            a.Eh[m * 416 + c] = h;
            a.El[m * 416 + c] = l;
        }
    } else {
        if (blockIdx.x >= 512) {
            if (blockIdx.x == 512) a.bars[tid] = 0;   // zero 256 barrier slots
            return;
        }
        // Wfc[r,c] = sum_n wf[r,n]*wc[n,c], r < 512
        if (tid >= 64) return;
        int r = blockIdx.x;
        int l = tid;
        float p[6] = {0,0,0,0,0,0};
        const float* row = a.wf + r * 512;
        #pragma unroll
        for (int k = 0; k < 8; ++k) {
            int n = l + 64 * k;
            float v = row[n];
            #pragma unroll
            for (int c = 0; c < 6; ++c) p[c] += v * a.wc[n * 6 + c];
        }
        #pragma unroll
        for (int c = 0; c < 6; ++c)
            for (int off = 32; off >= 1; off >>= 1) p[c] += __shfl_xor(p[c], off, 64);
        if (l == 0) {
            #pragma unroll
            for (int c = 0; c < 6; ++c) a.Wfc[r * 6 + c] = p[c];
        }
    }
}

// ---------------- conv256 body (M16/N64 tile) ----------------
__device__ void conv256_body(int mt, int n0, int tid,
        const unsigned short* __restrict__ Xih, const unsigned short* __restrict__ Xil,
        const unsigned short* __restrict__ Bh, const unsigned short* __restrict__ Bl,
        const float* __restrict__ bias, int outmode,
        unsigned short* __restrict__ Xoh, unsigned short* __restrict__ Xol,
        float* __restrict__ fout,
        unsigned short* xsh, unsigned short* xsl) {
    int p0 = mt * 16;
    int b = p0 >> 7, l0 = p0 & 127;
    for (int i = tid; i < 2 * 640; i += 256) {
        int sel = i >= 640;
        int u2 = sel ? i - 640 : i;
        int j = u2 >> 5, cg = u2 & 31;
        int l = l0 - 2 + j;
        short8 v = {0,0,0,0,0,0,0,0};
        if (l >= 0 && l < 128) {
            const unsigned short* src = (sel ? Xil : Xih) + (b * 128 + l) * 256 + cg * 8;
            v = *(const short8*)src;
        }
        *(short8*)((sel ? xsl : xsh) + j * 264 + cg * 8) = v;
    }
    __syncthreads();
    int w = tid >> 6, lane = tid & 63;
    int m = lane & 15, q = lane >> 4;
    int nB = n0 + w * 16 + m;
    floatx4 acc0 = {0,0,0,0}, acc1 = {0,0,0,0}, acc2 = {0,0,0,0};
    for (int kk = 0; kk < 5; ++kk) {
        const unsigned short* arh = xsh + (m + kk) * 264;
        const unsigned short* arl = xsl + (m + kk) * 264;
        #pragma unroll
        for (int u = 0; u < 8; ++u) {
            short8 ah = *(const short8*)(arh + u * 32 + q * 8);
            short8 al = *(const short8*)(arl + u * 32 + q * 8);
            int boff = (((kk * 32 + u * 4 + q) * 256) + nB) * 8;
            short8 bh = *(const short8*)(Bh + boff);
            short8 bl = *(const short8*)(Bl + boff);
            acc0 = __builtin_amdgcn_mfma_f32_16x16x32_bf16(ah, bh, acc0, 0, 0, 0);
            acc1 = __builtin_amdgcn_mfma_f32_16x16x32_bf16(ah, bl, acc1, 0, 0, 0);
            acc2 = __builtin_amdgcn_mfma_f32_16x16x32_bf16(al, bh, acc2, 0, 0, 0);
        }
    }
    __syncthreads();
    float* fl = (float*)xsh;   // 16 x 68 tile
    #pragma unroll
    for (int reg = 0; reg < 4; ++reg)
        fl[(q * 4 + reg) * 68 + w * 16 + m] = acc0[reg] + acc1[reg] + acc2[reg];
    __syncthreads();
    #pragma unroll
    for (int i = 0; i < 4; ++i) {
        int e = tid + 256 * i;
        int mm = e >> 6, nn = e & 63;
        float val = fl[mm * 68 + nn] + bias[n0 + nn];
        val = fmaxf(val, 0.f);
        int o = (p0 + mm) * 256 + n0 + nn;
        if (outmode == 0) {
            unsigned short h, l; split2(val, h, l);
            Xoh[o] = h; Xol[o] = l;
        } else {
            fout[o] = val;
        }
    }
    __syncthreads();   // protect LDS reuse across phases
}

// ---------------- persistent fused kernel: conv1(+precomp2) -> c3 -> c4 -> c5 -> qv ----------------
struct ConvArgs {
    const unsigned short *Eh, *El, *B1h, *B1l, *B2h, *B2l;
    const unsigned short *B3h, *B3l, *B4h, *B4l, *B5h, *B5l;
    unsigned short *X3h, *X3l, *X4h, *X4l;
    const float *b1, *b2, *b3, *b4, *b5;
    const float *wf, *bf, *wc, *Wfc;
    float *U;
    float *bufB;
    const float *wq, *bq, *wv, *bv;
    float *qb, *vb;
    int *bars;
};
__global__ __launch_bounds__(256, 2) void conv_all(ConvArgs a) {
    __shared__ __align__(16) unsigned short xsh[20 * 424];
    __shared__ __align__(16) unsigned short xsl[20 * 424];
    int bid = blockIdx.x;        // 0..319
    int tid = threadIdx.x;
    int by = bid >> 6, mt = bid & 63;

    // ---- phase 1: conv1 (by 0..3) + precomp2 (by==4) ----
    if (by == 4) {
        if (tid < 64) {
            int l = tid;
            for (int i = 0; i < 9; ++i) {
                int r = mt + 64 * i;
                if (r >= 531) break;
                const float* row = (r < 530) ? (a.wf + r * 512) : a.bf;
                float p[12];
                #pragma unroll
                for (int c = 0; c < 12; ++c) p[c] = 0.f;
                #pragma unroll
                for (int k = 0; k < 8; ++k) {
                    int n = l + 64 * k;
                    float v = row[n];
                    #pragma unroll
                    for (int c = 0; c < 6; ++c) {
                        p[c]     += v * a.wc[n * 6 + c];
                        p[c + 6] += v * a.Wfc[n * 6 + c];
                    }
                }
                #pragma unroll
                for (int c = 0; c < 12; ++c)
                    for (int off = 32; off >= 1; off >>= 1) p[c] += __shfl_xor(p[c], off, 64);
                if (l == 0) {
                    #pragma unroll
                    for (int c = 0; c < 12; ++c) a.U[r * 12 + c] = p[c];
                }
            }
        }
    } else {
        int p0 = mt * 16;
        int b = p0 >> 7, l0 = p0 & 127;
        for (int i = tid; i < 2 * 1040; i += 256) {
            int sel = i >= 1040;
            int u2 = sel ? i - 1040 : i;
            int j = u2 / 52, cg = u2 % 52;
            int l = l0 - 2 + j;
            short8 v = {0,0,0,0,0,0,0,0};
            if (l >= 0 && l < 128) {
                const unsigned short* src = (sel ? a.El : a.Eh) + (b * 128 + l) * 416 + cg * 8;
                v = *(const short8*)src;
            }
            *(short8*)((sel ? xsl : xsh) + j * 424 + cg * 8) = v;
        }
        __syncthreads();
        int w = tid >> 6, lane = tid & 63;
        int m = lane & 15, q = lane >> 4;
        bool br2 = (by >= 2);
        int n0b = (by & 1) * 64;
        int nB = n0b + w * 16 + m;
        floatx4 acc0 = {0,0,0,0}, acc1 = {0,0,0,0}, acc2 = {0,0,0,0};
        if (!br2) {
            for (int kk = 0; kk < 5; ++kk) {
                const unsigned short* arh = xsh + (m + kk) * 424;
                const unsigned short* arl = xsl + (m + kk) * 424;
                #pragma unroll
                for (int u = 0; u < 13; ++u) {
                    short8 ah = *(const short8*)(arh + u * 32 + q * 8);
                    short8 al = *(const short8*)(arl + u * 32 + q * 8);
                    int boff = (((kk * 52 + u * 4 + q) * 128) + nB) * 8;
                    short8 bh = *(const short8*)(a.B1h + boff);
                    short8 bl = *(const short8*)(a.B1l + boff);
                    acc0 = __builtin_amdgcn_mfma_f32_16x16x32_bf16(ah, bh, acc0, 0, 0, 0);
                    acc1 = __builtin_amdgcn_mfma_f32_16x16x32_bf16(ah, bl, acc1, 0, 0, 0);
                    acc2 = __builtin_amdgcn_mfma_f32_16x16x32_bf16(al, bh, acc2, 0, 0, 0);
                }
            }
        } else {
            for (int kk = 0; kk < 3; ++kk) {
                const unsigned short* arh = xsh + (m + kk + 1) * 424;
                const unsigned short* arl = xsl + (m + kk + 1) * 424;
                #pragma unroll
                for (int u = 0; u < 13; ++u) {
                    short8 ah = *(const short8*)(arh + u * 32 + q * 8);
                    short8 al = *(const short8*)(arl + u * 32 + q * 8);
                    int boff = (((kk * 52 + u * 4 + q) * 128) + nB) * 8;
                    short8 bh = *(const short8*)(a.B2h + boff);
                    short8 bl = *(const short8*)(a.B2l + boff);
                    acc0 = __builtin_amdgcn_mfma_f32_16x16x32_bf16(ah, bh, acc0, 0, 0, 0);
                    acc1 = __builtin_amdgcn_mfma_f32_16x16x32_bf16(ah, bl, acc1, 0, 0, 0);
                    acc2 = __builtin_amdgcn_mfma_f32_16x16x32_bf16(al, bh, acc2, 0, 0, 0);
                }
            }
        }
        __syncthreads();
        float* fl = (float*)xsh;   // 16 x 68 tile
        #pragma unroll
        for (int reg = 0; reg < 4; ++reg)
            fl[(q * 4 + reg) * 68 + w * 16 + m] = acc0[reg] + acc1[reg] + acc2[reg];
        __syncthreads();
        int ocb = br2 ? 128 + n0b : n0b;
        const float* bias = br2 ? a.b2 : a.b1;
        #pragma unroll
        for (int i = 0; i < 4; ++i) {
            int e = tid + 256 * i;
            int mm = e >> 6, nn = e & 63;
            float val = fl[mm * 68 + nn] + bias[n0b + nn];
            val = fmaxf(val, 0.f);
            unsigned short h, l; split2(val, h, l);
            int o = (p0 + mm) * 256 + ocb + nn;
            a.X3h[o] = h; a.X3l[o] = l;
        }
        __syncthreads();
    }
    gbar(a.bars, 0, CONV_BLOCKS);

    // ---- phase 2: conv3 (X3 -> X4) ----
    if (bid < 256)
        conv256_body(bid & 63, (bid >> 6) * 64, tid, a.X3h, a.X3l, a.B3h, a.B3l,
                     a.b3, 0, a.X4h, a.X4l, nullptr, xsh, xsl);
    gbar(a.bars, 1, CONV_BLOCKS);

    // ---- phase 3: conv4 (X4 -> X3) ----
    if (bid < 256)
        conv256_body(bid & 63, (bid >> 6) * 64, tid, a.X4h, a.X4l, a.B4h, a.B4l,
                     a.b4, 0, a.X3h, a.X3l, nullptr, xsh, xsl);
    gbar(a.bars, 2, CONV_BLOCKS);

    // ---- phase 4: conv5 (X3 -> bufB fp32) ----
    if (bid < 256)
        conv256_body(bid & 63, (bid >> 6) * 64, tid, a.X3h, a.X3l, a.B5h, a.B5l,
                     a.b5, 1, nullptr, nullptr, a.bufB, xsh, xsl);
    gbar(a.bars, 3, CONV_BLOCKS);

    // ---- phase 5: qv projection (work items: 1024 tokens x 128 (2x64)) ----
    #pragma unroll
    for (int k = 0; k < 2; ++k) {
        int item = bid * 256 + tid + CONV_BLOCKS * 256 * k;
        if (item >= 131072) break;
        int m = item >> 7, r = item & 127;
        int w = r >> 6, d = r & 63;
        if (d < 50) {
            const float* W = w ? a.wv : a.wq;
            float acc = w ? a.bv[d] : a.bq[d];
            const float* xm = a.bufB + m * 256;
            #pragma unroll 8
            for (int c = 0; c < 256; ++c) acc += xm[c] * W[c * 50 + d];
            (w ? a.vb : a.qb)[m * 50 + d] = acc;
        }
    }
}

// ---------------- attention v2 (+ fused f0/g0) ----------------
__global__ __launch_bounds__(256) void attn_v2(const float* __restrict__ xc,
        const float* __restrict__ q, const float* __restrict__ v,
        const float* __restrict__ vv, const float* __restrict__ xmask,
        const float* __restrict__ wc, const float* __restrict__ bc,
        float* __restrict__ xc2, float* __restrict__ f0, float* __restrict__ g0) {
    __shared__ float vs[128 * 50];   // 25.6 KB
    __shared__ float spart[128], aarr[128], xrow[256], qrow[52], vvs[52], red[4];
    int bi = blockIdx.x;             // b*L + i
    int b = bi >> 7;
    int tid = threadIdx.x;
    for (int idx = tid; idx < 128 * 50; idx += 256) vs[idx] = v[b * 6400 + idx];
    if (tid < 50) { qrow[tid] = q[bi * 50 + tid]; vvs[tid] = vv[tid]; }
    __syncthreads();
    int j = tid & 127, half = tid >> 7;
    int d0 = half * 25;
    const float* vj = vs + j * 50 + d0;
    float s = 0.f;
    #pragma unroll
    for (int d = 0; d < 25; ++d) {
        float x = qrow[d0 + d] + vj[d];
        float e = __expf(2.f * x);               // tanh(x) = 1 - 2/(e^(2x)+1)
        s += (1.f - 2.f / (e + 1.f)) * vvs[d0 + d];
    }
    if (half) spart[j] = s;
    __syncthreads();
    float stot = 0.f;
    if (!half) {
        stot = s + spart[j];
        if (xmask[b * LSEQ + j] == 0.f) stot = -1e9f;
    }
    if (tid < 128) {
        float m = stot;
        #pragma unroll
        for (int off = 32; off >= 1; off >>= 1) m = fmaxf(m, __shfl_xor(m, off, 64));
        if ((tid & 63) == 0) red[tid >> 6] = m;
    }
    __syncthreads();
    float mx = fmaxf(red[0], red[1]);
    float e = 0.f;
    if (tid < 128) {
        e = __expf(stot - mx);
        float su = e;
        #pragma unroll
        for (int off = 32; off >= 1; off >>= 1) su += __shfl_xor(su, off, 64);
        if ((tid & 63) == 0) red[2 + (tid >> 6)] = su;
    }
    __syncthreads();
    float denom = red[2] + red[3];
    if (tid < 128) aarr[j] = e / denom;
    __syncthreads();
    float maskI = xmask[bi];
    const float* xcb = xc + b * LSEQ * 256;
    float acc = 0.f;
    #pragma unroll 8
    for (int jj = 0; jj < 128; ++jj) acc += aarr[jj] * xcb[jj * 256 + tid];
    float val = xc[bi * 256 + tid] + acc * maskI;
    xc2[bi * 256 + tid] = val;
    xrow[tid] = val;
    __syncthreads();
    int grp = tid >> 4, l16 = tid & 15;
    if (grp < 12) {
        int c = grp % 6, gsel = grp / 6;
        const float* wcc = wc + gsel * 256 * 6 + c;
        float a = 0.f;
        #pragma unroll
        for (int ch = l16; ch < 256; ch += 16) a += xrow[ch] * wcc[ch * 6];
        #pragma unroll
        for (int off = 8; off >= 1; off >>= 1) a += __shfl_down(a, off, 16);
        if (l16 == 0) {
            if (gsel == 0) f0[bi * 6 + c] = a + bc[c];
            else           g0[bi * 6 + c] = a;
        }
    }
}

// ---------------- hop1: fused lm_scan(f0,g0) + hopfold ----------------
__global__ __launch_bounds__(256) void hop1_kernel(const float* __restrict__ xc2,
        const float* __restrict__ U, const float* __restrict__ f0,
        const float* __restrict__ g0, const float* __restrict__ bc,
        float* __restrict__ outF, float* __restrict__ outG) {
    __shared__ float sf0[768], sg0[768], sfw[768], sgw[768], lms[768];
    int b = blockIdx.x >> 4, grp = blockIdx.x & 15;
    int tid = threadIdx.x;
    for (int i = tid; i < 768; i += 256) {
        sf0[i] = f0[b * 768 + i];
        sg0[i] = g0[b * 768 + i];
    }
    __syncthreads();
    int p = tid;
    float fv[6], gv[6], pf[6], sx[6];
    if (p < 128) {
        #pragma unroll
        for (int c = 0; c < 6; ++c) {
            fv[c] = sf0[p * 6 + c]; gv[c] = sg0[p * 6 + c];
            pf[c] = fv[c]; sx[c] = gv[c];
            sfw[p * 6 + c] = fv[c]; sgw[p * 6 + c] = gv[c];
        }
    }
    __syncthreads();
    #pragma unroll
    for (int off = 1; off < 128; off <<= 1) {
        float av[6], dv[6];
        if (p < 128) {
            #pragma unroll
            for (int c = 0; c < 6; ++c) {
                av[c] = (p >= off) ? sfw[(p - off) * 6 + c] : -INFINITY;
                dv[c] = (p + off < 128) ? sgw[(p + off) * 6 + c] : -INFINITY;
            }
        }
        __syncthreads();
        if (p < 128) {
            #pragma unroll
            for (int c = 0; c < 6; ++c) {
                pf[c] = fmaxf(pf[c], av[c]); sx[c] = fmaxf(sx[c], dv[c]);
                sfw[p * 6 + c] = pf[c]; sgw[p * 6 + c] = sx[c];
            }
        }
        __syncthreads();
    }
    if (p < 128) {
        #pragma unroll
        for (int c = 0; c < 6; ++c) {
            float M1 = pf[c] + gv[c];
            if (p < LSEQ - 1) M1 = fmaxf(M1, 0.f);
            float M2 = fv[c] + sx[c];
            if (p > 0) M2 = fmaxf(M2, 0.f);
            lms[p * 6 + c] = fmaxf(M1, M2);
        }
    }
    __syncthreads();
    int t = tid >> 5, lane = tid & 31;
    int ptok = grp * 8 + t;
    int m = b * 128 + ptok;
    float p24[24];
    #pragma unroll
    for (int c = 0; c < 24; ++c) p24[c] = 0.f;
    const floatx4* U4 = (const floatx4*)U;
    const float* xm = xc2 + m * 256;
    #pragma unroll
    for (int kk = 0; kk < 8; ++kk) {
        int k = lane + 32 * kk;
        float a = xm[k];
        floatx4 u0[3], u1[3];
        #pragma unroll
        for (int t3 = 0; t3 < 3; ++t3) { u0[t3] = U4[k * 3 + t3]; u1[t3] = U4[(256 + k) * 3 + t3]; }
        #pragma unroll
        for (int t3 = 0; t3 < 3; ++t3)
            #pragma unroll
            for (int qd = 0; qd < 4; ++qd) {
                p24[t3 * 4 + qd]      += a * u0[t3][qd];
                p24[12 + t3 * 4 + qd] += a * u1[t3][qd];
            }
    }
    #pragma unroll
    for (int c = 0; c < 24; ++c)
        for (int off = 16; off >= 1; off >>= 1) p24[c] += __shfl_xor(p24[c], off, 32);
    if (lane < 12) {
        int c = lane;
        float s0 = p24[c], s1 = p24[12 + c];
        #pragma unroll
        for (int jj = 0; jj < 6; ++jj) {
            float lmv = lms[ptok * 6 + jj];
            float f0v = sf0[ptok * 6 + jj];
            float g0v = sg0[ptok * 6 + jj];
            float dbv = U[(524 + jj) * 12 + c];
            s0 += lmv * U[(512 + jj) * 12 + c] + f0v * dbv;
            s1 += lmv * U[(518 + jj) * 12 + c] + g0v * dbv;
        }
        s0 += U[530 * 12 + c];
        if (c < 6) s0 += bc[c];
        outF[m * 12 + c] = s0;
        outG[m * 12 + c] = s1;
    }
}

// ---------------- hop2: fused lm_scan(f1,g1) + f2g2 + writeout ----------------
__global__ __launch_bounds__(256) void hop2_kernel(const float* __restrict__ f1phi,
        const float* __restrict__ g1gam, const float* __restrict__ U,
        const float* __restrict__ bc, float* __restrict__ out) {
    __shared__ float f1s[128 * 12], g1s[128 * 12];
    __shared__ float sfw[768], sgw[768], lm1s[768], f2s[768], g2s[768];
    __shared__ float Us[228], bcs[6];
    int b = blockIdx.x >> 4, ys = blockIdx.x & 15;
    int tid = threadIdx.x;
    for (int i = tid; i < 1536; i += 256) {
        f1s[i] = f1phi[b * 1536 + i];
        g1s[i] = g1gam[b * 1536 + i];
    }
    if (tid < 228) Us[tid] = U[512 * 12 + tid];
    if (tid < 6) bcs[tid] = bc[tid];
    __syncthreads();
    int p = tid;
    float fv[6], gv[6], pf[6], sx[6];
    if (p < 128) {
        #pragma unroll
        for (int c = 0; c < 6; ++c) {
            fv[c] = f1s[p * 12 + c]; gv[c] = g1s[p * 12 + c];
            pf[c] = fv[c]; sx[c] = gv[c];
            sfw[p * 6 + c] = fv[c]; sgw[p * 6 + c] = gv[c];
        }
    }
    __syncthreads();
    #pragma unroll
    for (int off = 1; off < 128; off <<= 1) {
        float av[6], dv[6];
        if (p < 128) {
            #pragma unroll
            for (int c = 0; c < 6; ++c) {
                av[c] = (p >= off) ? sfw[(p - off) * 6 + c] : -INFINITY;
                dv[c] = (p + off < 128) ? sgw[(p + off) * 6 + c] : -INFINITY;
            }
        }
        __syncthreads();
        if (p < 128) {
            #pragma unroll
            for (int c = 0; c < 6; ++c) {
                pf[c] = fmaxf(pf[c], av[c]); sx[c] = fmaxf(sx[c], dv[c]);
                sfw[p * 6 + c] = pf[c]; sgw[p * 6 + c] = sx[c];
            }
        }
        __syncthreads();
    }
    if (p < 128) {
        #pragma unroll
        for (int c = 0; c < 6; ++c) {
            float M1 = pf[c] + gv[c];
            if (p < LSEQ - 1) M1 = fmaxf(M1, 0.f);
            float M2 = fv[c] + sx[c];
            if (p > 0) M2 = fmaxf(M2, 0.f);
            lm1s[p * 6 + c] = fmaxf(M1, M2);
        }
    }
    __syncthreads();
    if (p < 128) {
        float lmv[6], f1v[6], g1v[6];
        #pragma unroll
        for (int jj = 0; jj < 6; ++jj) {
            lmv[jj] = lm1s[p * 6 + jj];
            f1v[jj] = f1s[p * 12 + jj];
            g1v[jj] = g1s[p * 12 + jj];
        }
        #pragma unroll
        for (int c = 0; c < 6; ++c) {
            float sf = f1s[p * 12 + 6 + c] + Us[18 * 12 + c] + bcs[c];
            float sg = g1s[p * 12 + 6 + c];
            #pragma unroll
            for (int jj = 0; jj < 6; ++jj) {
                sf += lmv[jj] * Us[jj * 12 + c]       + f1v[jj] * Us[(12 + jj) * 12 + c];
                sg += lmv[jj] * Us[(6 + jj) * 12 + c] + g1v[jj] * Us[(12 + jj) * 12 + c];
            }
            f2s[p * 6 + c] = sf;
            g2s[p * 6 + c] = sg;
        }
    }
    __syncthreads();
    floatx4* out4 = (floatx4*)out;
    for (int e = tid; e < 1536; e += 256) {
        int i = e / 12, part = e - i * 12;
        floatx4 wv;
        #pragma unroll
        for (int qd = 0; qd < 4; ++qd) {
            int idx = part * 4 + qd;          // [0,48)
            int jj = idx / 6, c = idx - jj * 6;
            wv[qd] = f2s[i * 6 + c] + g2s[(ys * 8 + jj) * 6 + c];
        }
        out4[(b * 128 + i) * 192 + ys * 12 + part] = wv;
    }
}

extern "C" void kernel_launch(void* const* d_in, const int* in_sizes, int n_in,
                              void* d_out, int out_size, void* d_ws, size_t ws_size,
                              hipStream_t stream) {
    const int*   x     = (const int*)d_in[0];
    const float* xmask = (const float*)d_in[2];
    const float* gen   = (const float*)d_in[3];
    const float* dom   = (const float*)d_in[4];
    const float* w1    = (const float*)d_in[5];
    const float* b1    = (const float*)d_in[6];
    const float* w2    = (const float*)d_in[7];
    const float* b2    = (const float*)d_in[8];
    const float* w3    = (const float*)d_in[9];
    const float* b3    = (const float*)d_in[10];
    const float* w4    = (const float*)d_in[11];
    const float* b4    = (const float*)d_in[12];
    const float* w5    = (const float*)d_in[13];
    const float* b5    = (const float*)d_in[14];
    const float* wq    = (const float*)d_in[15];
    const float* bq    = (const float*)d_in[16];
    const float* wv    = (const float*)d_in[17];
    const float* bv    = (const float*)d_in[18];
    const float* vv    = (const float*)d_in[19];
    const float* wf    = (const float*)d_in[20];
    const float* bf    = (const float*)d_in[21];
    const float* wc    = (const float*)d_in[22];
    const float* bc    = (const float*)d_in[23];

    // fp32 region
    float* fb = (float*)d_ws;
    float* bufB  = fb;                   // 262144  (xc, conv5 out)
    float* xc2   = bufB  + 262144;       // 262144
    float* qb    = xc2   + 262144;       // 51200
    float* vb    = qb    + 51200;        // 51200
    float* Wfc   = vb    + 51200;        // 3072
    float* U     = Wfc   + 3072;         // 6376 (pad)
    float* f0    = U     + 6376;         // 6144
    float* g0    = f0    + 6144;
    float* lm0   = g0    + 6144;         // reused: grid-barrier counters (256 ints)
    float* lm1   = lm0   + 6144;
    float* f1phi = lm1   + 6144;         // 12288
    float* g1gam = f1phi + 12288;        // 12288
    float* f2    = g1gam + 12288;        // 6144
    float* g2    = f2    + 6144;
    int* bars = (int*)lm0;
    (void)lm1; (void)f2;
    // bf16 (ushort) region, 16B aligned
    unsigned short* sb = (unsigned short*)(g2 + 6144 + 32);
    unsigned short* Eh  = sb;             sb += 425984;  // 1024*416
    unsigned short* El  = sb;             sb += 425984;
    unsigned short* B1h = sb;             sb += 266240;  // 5*52*128*8
    unsigned short* B1l = sb;             sb += 266240;
    unsigned short* B2h = sb;             sb += 159744;  // 3*52*128*8
    unsigned short* B2l = sb;             sb += 159744;
    unsigned short* B3h = sb;             sb += 327680;  // 5*32*256*8
    unsigned short* B3l = sb;             sb += 327680;
    unsigned short* B4h = sb;             sb += 327680;
    unsigned short* B4l = sb;             sb += 327680;
    unsigned short* B5h = sb;             sb += 327680;
    unsigned short* B5l = sb;             sb += 327680;
    unsigned short* X3h = sb;             sb += 262144;  // 1024*256
    unsigned short* X3l = sb;             sb += 262144;
    unsigned short* X4h = sb;             sb += 262144;
    unsigned short* X4l = sb;             sb += 262144;

    // --- staging (also zeroes barrier counters) ---
    PreArgs pa;
    pa.w1 = w1; pa.w2 = w2; pa.w3 = w3; pa.w4 = w4; pa.w5 = w5;
    pa.B1h = B1h; pa.B1l = B1l; pa.B2h = B2h; pa.B2l = B2l;
    pa.B3h = B3h; pa.B3l = B3l; pa.B4h = B4h; pa.B4l = B4l;
    pa.B5h = B5h; pa.B5l = B5l;
    pa.x = x; pa.gen = gen; pa.dom = dom; pa.Eh = Eh; pa.El = El;
    pa.wf = wf; pa.wc = wc; pa.Wfc = Wfc; pa.bars = bars;
    stage_kernel<<<dim3(1280, 7), 256, 0, stream>>>(pa);

    // --- persistent fused convs + qv (software grid barriers) ---
    ConvArgs ca;
    ca.Eh = Eh; ca.El = El; ca.B1h = B1h; ca.B1l = B1l; ca.B2h = B2h; ca.B2l = B2l;
    ca.B3h = B3h; ca.B3l = B3l; ca.B4h = B4h; ca.B4l = B4l; ca.B5h = B5h; ca.B5l = B5l;
    ca.X3h = X3h; ca.X3l = X3l; ca.X4h = X4h; ca.X4l = X4l;
    ca.b1 = b1; ca.b2 = b2; ca.b3 = b3; ca.b4 = b4; ca.b5 = b5;
    ca.wf = wf; ca.bf = bf; ca.wc = wc; ca.Wfc = Wfc; ca.U = U; ca.bufB = bufB;
    ca.wq = wq; ca.bq = bq; ca.wv = wv; ca.bv = bv; ca.qb = qb; ca.vb = vb;
    ca.bars = bars;
    conv_all<<<CONV_BLOCKS, 256, 0, stream>>>(ca);

    // --- attention (+ fused f0/g0) ---
    attn_v2<<<M_TOK, 256, 0, stream>>>(bufB, qb, vb, vv, xmask, wc, bc, xc2, f0, g0);

    // --- hops: 2 fused kernels ---
    hop1_kernel<<<128, 256, 0, stream>>>(xc2, U, f0, g0, bc, f1phi, g1gam);
    hop2_kernel<<<128, 256, 0, stream>>>(f1phi, g1gam, U, bc, (float*)d_out);
}

// Round 3
// 243.608 us; speedup vs baseline: 1.8676x; 1.8676x over previous
//
#include <hip/hip_runtime.h>
#include <math.h>

#define LSEQ 128
#define BB 8
#define M_TOK (BB*LSEQ)   // 1024

typedef __attribute__((ext_vector_type(8))) short short8;
typedef __attribute__((ext_vector_type(4))) float floatx4;

__device__ __forceinline__ unsigned short bf16_rne(float v) {
    union { float f; unsigned u; } a; a.f = v;
    return (unsigned short)((a.u + 0x7fffu + ((a.u >> 16) & 1u)) >> 16);
}
__device__ __forceinline__ float bf16_to_f(unsigned short h) {
    union { unsigned u; float f; } b; b.u = ((unsigned)h) << 16;
    return b.f;
}
__device__ __forceinline__ void split2(float v, unsigned short& h, unsigned short& l) {
    h = bf16_rne(v);
    l = bf16_rne(v - bf16_to_f(h));
}

// ---------------- staging: pack all conv weights (split bf16, MFMA B-layout),
// embedding gather+split, Wfc — one launch ----------------
struct PreArgs {
    const float *w1, *w2, *w3, *w4, *w5;
    unsigned short *B1h, *B1l, *B2h, *B2l, *B3h, *B3l, *B4h, *B4l, *B5h, *B5l;
    const int* x;
    const float* gen;
    const float* dom;
    unsigned short *Eh, *El;
    const float* wf;
    const float* wc;
    float* Wfc;
};
__global__ __launch_bounds__(256) void stage_kernel(PreArgs a) {
    int y = blockIdx.y;
    int tid = threadIdx.x;
    if (y < 3) {
        const float* w = (y == 0) ? a.w3 : (y == 1) ? a.w4 : a.w5;
        unsigned short* dh = (y == 0) ? a.B3h : (y == 1) ? a.B4h : a.B5h;
        unsigned short* dl = (y == 0) ? a.B3l : (y == 1) ? a.B4l : a.B5l;
        int idx = blockIdx.x * 256 + tid;          // < 327680 exactly
        int j = idx & 7;
        int n = (idx >> 3) & 255;
        int g = idx >> 11;
        int cg = g & 31, kk = g >> 5;
        int ci = cg * 8 + j;
        float v = w[(n * 256 + ci) * 5 + kk];
        unsigned short h, l; split2(v, h, l);
        dh[idx] = h; dl[idx] = l;
    } else if (y == 3) {
        int idx = blockIdx.x * 256 + tid;
        if (idx >= 5 * 52 * 128 * 8) return;
        int j = idx & 7;
        int n = (idx >> 3) & 127;
        int g = idx >> 10;
        int cg = g % 52, kk = g / 52;
        int ci = cg * 8 + j;
        float v = (ci < 400) ? a.w1[(n * 400 + ci) * 5 + kk] : 0.f;
        unsigned short h, l; split2(v, h, l);
        a.B1h[idx] = h; a.B1l[idx] = l;
    } else if (y == 4) {
        int idx = blockIdx.x * 256 + tid;
        if (idx >= 3 * 52 * 128 * 8) return;
        int j = idx & 7;
        int n = (idx >> 3) & 127;
        int g = idx >> 10;
        int cg = g % 52, kk = g / 52;
        int ci = cg * 8 + j;
        float v = (ci < 400) ? a.w2[(n * 400 + ci) * 3 + kk] : 0.f;
        unsigned short h, l; split2(v, h, l);
        a.B2h[idx] = h; a.B2l[idx] = l;
    } else if (y == 5) {
        int m = blockIdx.x;
        if (m >= M_TOK) return;
        int t = a.x[m];
        for (int c = tid; c < 416; c += 256) {
            float v = (c < 300) ? a.gen[t * 300 + c]
                    : (c < 400) ? a.dom[t * 100 + (c - 300)] : 0.f;
            unsigned short h, l; split2(v, h, l);
            a.Eh[m * 416 + c] = h;
            a.El[m * 416 + c] = l;
        }
    } else {
        // Wfc[r,c] = sum_n wf[r,n]*wc[n,c], r < 512
        int r = blockIdx.x;
        if (r >= 512 || tid >= 64) return;
        int l = tid;
        float p[6] = {0,0,0,0,0,0};
        const float* row = a.wf + r * 512;
        #pragma unroll
        for (int k = 0; k < 8; ++k) {
            int n = l + 64 * k;
            float v = row[n];
            #pragma unroll
            for (int c = 0; c < 6; ++c) p[c] += v * a.wc[n * 6 + c];
        }
        #pragma unroll
        for (int c = 0; c < 6; ++c)
            for (int off = 32; off >= 1; off >>= 1) p[c] += __shfl_xor(p[c], off, 64);
        if (l == 0) {
            #pragma unroll
            for (int c = 0; c < 6; ++c) a.Wfc[r * 6 + c] = p[c];
        }
    }
}

// ---------------- conv1 MFMA (+precomp2 on by==4) ----------------
__global__ __launch_bounds__(256) void conv1_mfma(
        const unsigned short* __restrict__ Eh, const unsigned short* __restrict__ El,
        const unsigned short* __restrict__ B1h, const unsigned short* __restrict__ B1l,
        const unsigned short* __restrict__ B2h, const unsigned short* __restrict__ B2l,
        const float* __restrict__ b1, const float* __restrict__ b2,
        unsigned short* __restrict__ Xoh, unsigned short* __restrict__ Xol,
        const float* __restrict__ wf, const float* __restrict__ bf,
        const float* __restrict__ wc, const float* __restrict__ Wfc,
        float* __restrict__ U) {
    __shared__ __align__(16) unsigned short xsh[20 * 424];
    __shared__ __align__(16) unsigned short xsl[20 * 424];
    int by = blockIdx.y;
    int tid = threadIdx.x;
    if (by == 4) {
        // precomp2: U[r,0:12] = row_r @ [wc | Wfc]
        if (tid >= 64) return;
        int l = tid;
        for (int i = 0; i < 9; ++i) {
            int r = blockIdx.x + 64 * i;
            if (r >= 531) break;
            const float* row = (r < 530) ? (wf + r * 512) : bf;
            float p[12];
            #pragma unroll
            for (int c = 0; c < 12; ++c) p[c] = 0.f;
            #pragma unroll
            for (int k = 0; k < 8; ++k) {
                int n = l + 64 * k;
                float v = row[n];
                #pragma unroll
                for (int c = 0; c < 6; ++c) {
                    p[c]     += v * wc[n * 6 + c];
                    p[c + 6] += v * Wfc[n * 6 + c];
                }
            }
            #pragma unroll
            for (int c = 0; c < 12; ++c)
                for (int off = 32; off >= 1; off >>= 1) p[c] += __shfl_xor(p[c], off, 64);
            if (l == 0) {
                #pragma unroll
                for (int c = 0; c < 12; ++c) U[r * 12 + c] = p[c];
            }
        }
        return;
    }
    int mt = blockIdx.x;
    int p0 = mt * 16;
    int b = p0 >> 7, l0 = p0 & 127;
    for (int i = tid; i < 2 * 1040; i += 256) {
        int sel = i >= 1040;
        int u2 = sel ? i - 1040 : i;
        int j = u2 / 52, cg = u2 % 52;
        int l = l0 - 2 + j;
        short8 v = {0,0,0,0,0,0,0,0};
        if (l >= 0 && l < 128) {
            const unsigned short* src = (sel ? El : Eh) + (b * 128 + l) * 416 + cg * 8;
            v = *(const short8*)src;
        }
        *(short8*)((sel ? xsl : xsh) + j * 424 + cg * 8) = v;
    }
    __syncthreads();
    int w = tid >> 6, lane = tid & 63;
    int m = lane & 15, q = lane >> 4;
    bool br2 = (by >= 2);
    int n0b = (by & 1) * 64;
    int nB = n0b + w * 16 + m;
    floatx4 acc0 = {0,0,0,0}, acc1 = {0,0,0,0}, acc2 = {0,0,0,0};
    if (!br2) {
        for (int kk = 0; kk < 5; ++kk) {
            const unsigned short* arh = xsh + (m + kk) * 424;
            const unsigned short* arl = xsl + (m + kk) * 424;
            #pragma unroll
            for (int u = 0; u < 13; ++u) {
                short8 ah = *(const short8*)(arh + u * 32 + q * 8);
                short8 al = *(const short8*)(arl + u * 32 + q * 8);
                int boff = (((kk * 52 + u * 4 + q) * 128) + nB) * 8;
                short8 bh = *(const short8*)(B1h + boff);
                short8 bl = *(const short8*)(B1l + boff);
                acc0 = __builtin_amdgcn_mfma_f32_16x16x32_bf16(ah, bh, acc0, 0, 0, 0);
                acc1 = __builtin_amdgcn_mfma_f32_16x16x32_bf16(ah, bl, acc1, 0, 0, 0);
                acc2 = __builtin_amdgcn_mfma_f32_16x16x32_bf16(al, bh, acc2, 0, 0, 0);
            }
        }
    } else {
        for (int kk = 0; kk < 3; ++kk) {
            const unsigned short* arh = xsh + (m + kk + 1) * 424;
            const unsigned short* arl = xsl + (m + kk + 1) * 424;
            #pragma unroll
            for (int u = 0; u < 13; ++u) {
                short8 ah = *(const short8*)(arh + u * 32 + q * 8);
                short8 al = *(const short8*)(arl + u * 32 + q * 8);
                int boff = (((kk * 52 + u * 4 + q) * 128) + nB) * 8;
                short8 bh = *(const short8*)(B2h + boff);
                short8 bl = *(const short8*)(B2l + boff);
                acc0 = __builtin_amdgcn_mfma_f32_16x16x32_bf16(ah, bh, acc0, 0, 0, 0);
                acc1 = __builtin_amdgcn_mfma_f32_16x16x32_bf16(ah, bl, acc1, 0, 0, 0);
                acc2 = __builtin_amdgcn_mfma_f32_16x16x32_bf16(al, bh, acc2, 0, 0, 0);
            }
        }
    }
    __syncthreads();
    float* fl = (float*)xsh;   // 16 x 68 tile
    #pragma unroll
    for (int reg = 0; reg < 4; ++reg)
        fl[(q * 4 + reg) * 68 + w * 16 + m] = acc0[reg] + acc1[reg] + acc2[reg];
    __syncthreads();
    int ocb = br2 ? 128 + n0b : n0b;
    const float* bias = br2 ? b2 : b1;
    #pragma unroll
    for (int i = 0; i < 4; ++i) {
        int e = tid + 256 * i;
        int mm = e >> 6, nn = e & 63;
        float val = fl[mm * 68 + nn] + bias[n0b + nn];
        val = fmaxf(val, 0.f);
        unsigned short h, l; split2(val, h, l);
        int o = (p0 + mm) * 256 + ocb + nn;
        Xoh[o] = h; Xol[o] = l;
    }
}

// ---------------- conv256 MFMA: 256->256, k=5, p=2, relu; M16/N64 tile ----------------
__global__ __launch_bounds__(256) void conv256_mfma(
        const unsigned short* __restrict__ Xih, const unsigned short* __restrict__ Xil,
        const unsigned short* __restrict__ Bh, const unsigned short* __restrict__ Bl,
        const float* __restrict__ bias, int outmode,
        unsigned short* __restrict__ Xoh, unsigned short* __restrict__ Xol,
        float* __restrict__ fout) {
    __shared__ __align__(16) unsigned short xsh[20 * 264];
    __shared__ __align__(16) unsigned short xsl[20 * 264];
    int mt = blockIdx.x;
    int p0 = mt * 16;
    int b = p0 >> 7, l0 = p0 & 127;
    int n0 = blockIdx.y * 64;
    int tid = threadIdx.x;
    for (int i = tid; i < 2 * 640; i += 256) {
        int sel = i >= 640;
        int u2 = sel ? i - 640 : i;
        int j = u2 >> 5, cg = u2 & 31;
        int l = l0 - 2 + j;
        short8 v = {0,0,0,0,0,0,0,0};
        if (l >= 0 && l < 128) {
            const unsigned short* src = (sel ? Xil : Xih) + (b * 128 + l) * 256 + cg * 8;
            v = *(const short8*)src;
        }
        *(short8*)((sel ? xsl : xsh) + j * 264 + cg * 8) = v;
    }
    __syncthreads();
    int w = tid >> 6, lane = tid & 63;
    int m = lane & 15, q = lane >> 4;
    int nB = n0 + w * 16 + m;
    floatx4 acc0 = {0,0,0,0}, acc1 = {0,0,0,0}, acc2 = {0,0,0,0};
    for (int kk = 0; kk < 5; ++kk) {
        const unsigned short* arh = xsh + (m + kk) * 264;
        const unsigned short* arl = xsl + (m + kk) * 264;
        #pragma unroll
        for (int u = 0; u < 8; ++u) {
            short8 ah = *(const short8*)(arh + u * 32 + q * 8);
            short8 al = *(const short8*)(arl + u * 32 + q * 8);
            int boff = (((kk * 32 + u * 4 + q) * 256) + nB) * 8;
            short8 bh = *(const short8*)(Bh + boff);
            short8 bl = *(const short8*)(Bl + boff);
            acc0 = __builtin_amdgcn_mfma_f32_16x16x32_bf16(ah, bh, acc0, 0, 0, 0);
            acc1 = __builtin_amdgcn_mfma_f32_16x16x32_bf16(ah, bl, acc1, 0, 0, 0);
            acc2 = __builtin_amdgcn_mfma_f32_16x16x32_bf16(al, bh, acc2, 0, 0, 0);
        }
    }
    __syncthreads();
    float* fl = (float*)xsh;   // 16 x 68 tile
    #pragma unroll
    for (int reg = 0; reg < 4; ++reg)
        fl[(q * 4 + reg) * 68 + w * 16 + m] = acc0[reg] + acc1[reg] + acc2[reg];
    __syncthreads();
    #pragma unroll
    for (int i = 0; i < 4; ++i) {
        int e = tid + 256 * i;
        int mm = e >> 6, nn = e & 63;
        float val = fl[mm * 68 + nn] + bias[n0 + nn];
        val = fmaxf(val, 0.f);
        int o = (p0 + mm) * 256 + n0 + nn;
        if (outmode == 0) {
            unsigned short h, l; split2(val, h, l);
            Xoh[o] = h; Xol[o] = l;
        } else {
            fout[o] = val;
        }
    }
}

// ---------------- q/v projection ----------------
__global__ __launch_bounds__(128) void qv_v2(const float* __restrict__ xc,
        const float* __restrict__ wq, const float* __restrict__ bq,
        const float* __restrict__ wv, const float* __restrict__ bv,
        float* __restrict__ q, float* __restrict__ v) {
    int m = blockIdx.x;
    int tid = threadIdx.x;
    int w = tid >> 6, d = tid & 63;
    if (d >= 50) return;
    const float* W = w ? wv : wq;
    float a = w ? bv[d] : bq[d];
    const float* xm = xc + m * 256;
    #pragma unroll 8
    for (int c = 0; c < 256; ++c) a += xm[c] * W[c * 50 + d];
    (w ? v : q)[m * 50 + d] = a;
}

// ---------------- attention v2 (+ fused f0/g0) ----------------
__global__ __launch_bounds__(256) void attn_v2(const float* __restrict__ xc,
        const float* __restrict__ q, const float* __restrict__ v,
        const float* __restrict__ vv, const float* __restrict__ xmask,
        const float* __restrict__ wc, const float* __restrict__ bc,
        float* __restrict__ xc2, float* __restrict__ f0, float* __restrict__ g0) {
    __shared__ float vs[128 * 50];   // 25.6 KB
    __shared__ float spart[128], aarr[128], xrow[256], qrow[52], vvs[52], red[4];
    int bi = blockIdx.x;             // b*L + i
    int b = bi >> 7;
    int tid = threadIdx.x;
    for (int idx = tid; idx < 128 * 50; idx += 256) vs[idx] = v[b * 6400 + idx];
    if (tid < 50) { qrow[tid] = q[bi * 50 + tid]; vvs[tid] = vv[tid]; }
    __syncthreads();
    int j = tid & 127, half = tid >> 7;
    int d0 = half * 25;
    const float* vj = vs + j * 50 + d0;
    float s = 0.f;
    #pragma unroll
    for (int d = 0; d < 25; ++d) {
        float x = qrow[d0 + d] + vj[d];
        float e = __expf(2.f * x);               // tanh(x) = 1 - 2/(e^(2x)+1)
        s += (1.f - 2.f / (e + 1.f)) * vvs[d0 + d];
    }
    if (half) spart[j] = s;
    __syncthreads();
    float stot = 0.f;
    if (!half) {
        stot = s + spart[j];
        if (xmask[b * LSEQ + j] == 0.f) stot = -1e9f;
    }
    if (tid < 128) {
        float m = stot;
        #pragma unroll
        for (int off = 32; off >= 1; off >>= 1) m = fmaxf(m, __shfl_xor(m, off, 64));
        if ((tid & 63) == 0) red[tid >> 6] = m;
    }
    __syncthreads();
    float mx = fmaxf(red[0], red[1]);
    float e = 0.f;
    if (tid < 128) {
        e = __expf(stot - mx);
        float su = e;
        #pragma unroll
        for (int off = 32; off >= 1; off >>= 1) su += __shfl_xor(su, off, 64);
        if ((tid & 63) == 0) red[2 + (tid >> 6)] = su;
    }
    __syncthreads();
    float denom = red[2] + red[3];
    if (tid < 128) aarr[j] = e / denom;
    __syncthreads();
    float maskI = xmask[bi];
    const float* xcb = xc + b * LSEQ * 256;
    float acc = 0.f;
    #pragma unroll 8
    for (int jj = 0; jj < 128; ++jj) acc += aarr[jj] * xcb[jj * 256 + tid];
    float val = xc[bi * 256 + tid] + acc * maskI;
    xc2[bi * 256 + tid] = val;
    xrow[tid] = val;
    __syncthreads();
    int grp = tid >> 4, l16 = tid & 15;
    if (grp < 12) {
        int c = grp % 6, gsel = grp / 6;
        const float* wcc = wc + gsel * 256 * 6 + c;
        float a = 0.f;
        #pragma unroll
        for (int ch = l16; ch < 256; ch += 16) a += xrow[ch] * wcc[ch * 6];
        #pragma unroll
        for (int off = 8; off >= 1; off >>= 1) a += __shfl_down(a, off, 16);
        if (l16 == 0) {
            if (gsel == 0) f0[bi * 6 + c] = a + bc[c];
            else           g0[bi * 6 + c] = a;
        }
    }
}

// ---------------- hop1: fused lm_scan(f0,g0) + hopfold ----------------
// grid: 128 blocks = b(8) x grp(16); block = 8 tokens x 32 lanes
__global__ __launch_bounds__(256) void hop1_kernel(const float* __restrict__ xc2,
        const float* __restrict__ U, const float* __restrict__ f0,
        const float* __restrict__ g0, const float* __restrict__ bc,
        float* __restrict__ outF, float* __restrict__ outG) {
    __shared__ float sf0[768], sg0[768], sfw[768], sgw[768], lms[768];
    int b = blockIdx.x >> 4, grp = blockIdx.x & 15;
    int tid = threadIdx.x;
    for (int i = tid; i < 768; i += 256) {
        sf0[i] = f0[b * 768 + i];
        sg0[i] = g0[b * 768 + i];
    }
    __syncthreads();
    int p = tid;
    float fv[6], gv[6], pf[6], sx[6];
    if (p < 128) {
        #pragma unroll
        for (int c = 0; c < 6; ++c) {
            fv[c] = sf0[p * 6 + c]; gv[c] = sg0[p * 6 + c];
            pf[c] = fv[c]; sx[c] = gv[c];
            sfw[p * 6 + c] = fv[c]; sgw[p * 6 + c] = gv[c];
        }
    }
    __syncthreads();
    #pragma unroll
    for (int off = 1; off < 128; off <<= 1) {
        float av[6], dv[6];
        if (p < 128) {
            #pragma unroll
            for (int c = 0; c < 6; ++c) {
                av[c] = (p >= off) ? sfw[(p - off) * 6 + c] : -INFINITY;
                dv[c] = (p + off < 128) ? sgw[(p + off) * 6 + c] : -INFINITY;
            }
        }
        __syncthreads();
        if (p < 128) {
            #pragma unroll
            for (int c = 0; c < 6; ++c) {
                pf[c] = fmaxf(pf[c], av[c]); sx[c] = fmaxf(sx[c], dv[c]);
                sfw[p * 6 + c] = pf[c]; sgw[p * 6 + c] = sx[c];
            }
        }
        __syncthreads();
    }
    if (p < 128) {
        #pragma unroll
        for (int c = 0; c < 6; ++c) {
            float M1 = pf[c] + gv[c];
            if (p < LSEQ - 1) M1 = fmaxf(M1, 0.f);
            float M2 = fv[c] + sx[c];
            if (p > 0) M2 = fmaxf(M2, 0.f);
            lms[p * 6 + c] = fmaxf(M1, M2);
        }
    }
    __syncthreads();
    int t = tid >> 5, lane = tid & 31;
    int ptok = grp * 8 + t;
    int m = b * 128 + ptok;
    float p24[24];
    #pragma unroll
    for (int c = 0; c < 24; ++c) p24[c] = 0.f;
    const floatx4* U4 = (const floatx4*)U;
    const float* xm = xc2 + m * 256;
    #pragma unroll
    for (int kk = 0; kk < 8; ++kk) {
        int k = lane + 32 * kk;
        float a = xm[k];
        floatx4 u0[3], u1[3];
        #pragma unroll
        for (int t3 = 0; t3 < 3; ++t3) { u0[t3] = U4[k * 3 + t3]; u1[t3] = U4[(256 + k) * 3 + t3]; }
        #pragma unroll
        for (int t3 = 0; t3 < 3; ++t3)
            #pragma unroll
            for (int qd = 0; qd < 4; ++qd) {
                p24[t3 * 4 + qd]      += a * u0[t3][qd];
                p24[12 + t3 * 4 + qd] += a * u1[t3][qd];
            }
    }
    #pragma unroll
    for (int c = 0; c < 24; ++c)
        for (int off = 16; off >= 1; off >>= 1) p24[c] += __shfl_xor(p24[c], off, 32);
    if (lane < 12) {
        int c = lane;
        float s0 = p24[c], s1 = p24[12 + c];
        #pragma unroll
        for (int jj = 0; jj < 6; ++jj) {
            float lmv = lms[ptok * 6 + jj];
            float f0v = sf0[ptok * 6 + jj];
            float g0v = sg0[ptok * 6 + jj];
            float dbv = U[(524 + jj) * 12 + c];
            s0 += lmv * U[(512 + jj) * 12 + c] + f0v * dbv;
            s1 += lmv * U[(518 + jj) * 12 + c] + g0v * dbv;
        }
        s0 += U[530 * 12 + c];
        if (c < 6) s0 += bc[c];
        outF[m * 12 + c] = s0;
        outG[m * 12 + c] = s1;
    }
}

// ---------------- hop2: fused lm_scan(f1,g1) + f2g2 + writeout ----------------
// grid: 128 blocks = b(8) x jslice(16); each block writes j in [ys*8, ys*8+8)
__global__ __launch_bounds__(256) void hop2_kernel(const float* __restrict__ f1phi,
        const float* __restrict__ g1gam, const float* __restrict__ U,
        const float* __restrict__ bc, float* __restrict__ out) {
    __shared__ float f1s[128 * 12], g1s[128 * 12];
    __shared__ float sfw[768], sgw[768], lm1s[768], f2s[768], g2s[768];
    __shared__ float Us[228], bcs[6];
    int b = blockIdx.x >> 4, ys = blockIdx.x & 15;
    int tid = threadIdx.x;
    for (int i = tid; i < 1536; i += 256) {
        f1s[i] = f1phi[b * 1536 + i];
        g1s[i] = g1gam[b * 1536 + i];
    }
    if (tid < 228) Us[tid] = U[512 * 12 + tid];
    if (tid < 6) bcs[tid] = bc[tid];
    __syncthreads();
    int p = tid;
    float fv[6], gv[6], pf[6], sx[6];
    if (p < 128) {
        #pragma unroll
        for (int c = 0; c < 6; ++c) {
            fv[c] = f1s[p * 12 + c]; gv[c] = g1s[p * 12 + c];
            pf[c] = fv[c]; sx[c] = gv[c];
            sfw[p * 6 + c] = fv[c]; sgw[p * 6 + c] = gv[c];
        }
    }
    __syncthreads();
    #pragma unroll
    for (int off = 1; off < 128; off <<= 1) {
        float av[6], dv[6];
        if (p < 128) {
            #pragma unroll
            for (int c = 0; c < 6; ++c) {
                av[c] = (p >= off) ? sfw[(p - off) * 6 + c] : -INFINITY;
                dv[c] = (p + off < 128) ? sgw[(p + off) * 6 + c] : -INFINITY;
            }
        }
        __syncthreads();
        if (p < 128) {
            #pragma unroll
            for (int c = 0; c < 6; ++c) {
                pf[c] = fmaxf(pf[c], av[c]); sx[c] = fmaxf(sx[c], dv[c]);
                sfw[p * 6 + c] = pf[c]; sgw[p * 6 + c] = sx[c];
            }
        }
        __syncthreads();
    }
    if (p < 128) {
        #pragma unroll
        for (int c = 0; c < 6; ++c) {
            float M1 = pf[c] + gv[c];
            if (p < LSEQ - 1) M1 = fmaxf(M1, 0.f);
            float M2 = fv[c] + sx[c];
            if (p > 0) M2 = fmaxf(M2, 0.f);
            lm1s[p * 6 + c] = fmaxf(M1, M2);
        }
    }
    __syncthreads();
    if (p < 128) {
        float lmv[6], f1v[6], g1v[6];
        #pragma unroll
        for (int jj = 0; jj < 6; ++jj) {
            lmv[jj] = lm1s[p * 6 + jj];
            f1v[jj] = f1s[p * 12 + jj];
            g1v[jj] = g1s[p * 12 + jj];
        }
        #pragma unroll
        for (int c = 0; c < 6; ++c) {
            float sf = f1s[p * 12 + 6 + c] + Us[18 * 12 + c] + bcs[c];
            float sg = g1s[p * 12 + 6 + c];
            #pragma unroll
            for (int jj = 0; jj < 6; ++jj) {
                sf += lmv[jj] * Us[jj * 12 + c]       + f1v[jj] * Us[(12 + jj) * 12 + c];
                sg += lmv[jj] * Us[(6 + jj) * 12 + c] + g1v[jj] * Us[(12 + jj) * 12 + c];
            }
            f2s[p * 6 + c] = sf;
            g2s[p * 6 + c] = sg;
        }
    }
    __syncthreads();
    floatx4* out4 = (floatx4*)out;
    for (int e = tid; e < 1536; e += 256) {
        int i = e / 12, part = e - i * 12;
        floatx4 wv;
        #pragma unroll
        for (int qd = 0; qd < 4; ++qd) {
            int idx = part * 4 + qd;          // [0,48)
            int jj = idx / 6, c = idx - jj * 6;
            wv[qd] = f2s[i * 6 + c] + g2s[(ys * 8 + jj) * 6 + c];
        }
        out4[(b * 128 + i) * 192 + ys * 12 + part] = wv;
    }
}

extern "C" void kernel_launch(void* const* d_in, const int* in_sizes, int n_in,
                              void* d_out, int out_size, void* d_ws, size_t ws_size,
                              hipStream_t stream) {
    const int*   x     = (const int*)d_in[0];
    const float* xmask = (const float*)d_in[2];
    const float* gen   = (const float*)d_in[3];
    const float* dom   = (const float*)d_in[4];
    const float* w1    = (const float*)d_in[5];
    const float* b1    = (const float*)d_in[6];
    const float* w2    = (const float*)d_in[7];
    const float* b2    = (const float*)d_in[8];
    const float* w3    = (const float*)d_in[9];
    const float* b3    = (const float*)d_in[10];
    const float* w4    = (const float*)d_in[11];
    const float* b4    = (const float*)d_in[12];
    const float* w5    = (const float*)d_in[13];
    const float* b5    = (const float*)d_in[14];
    const float* wq    = (const float*)d_in[15];
    const float* bq    = (const float*)d_in[16];
    const float* wv    = (const float*)d_in[17];
    const float* bv    = (const float*)d_in[18];
    const float* vv    = (const float*)d_in[19];
    const float* wf    = (const float*)d_in[20];
    const float* bf    = (const float*)d_in[21];
    const float* wc    = (const float*)d_in[22];
    const float* bc    = (const float*)d_in[23];

    // fp32 region
    float* fb = (float*)d_ws;
    float* bufB  = fb;                   // 262144  (xc, conv5 out)
    float* xc2   = bufB  + 262144;       // 262144
    float* qb    = xc2   + 262144;       // 51200
    float* vb    = qb    + 51200;        // 51200
    float* Wfc   = vb    + 51200;        // 3072
    float* U     = Wfc   + 3072;         // 6376 (pad)
    float* f0    = U     + 6376;         // 6144
    float* g0    = f0    + 6144;
    float* lm0   = g0    + 6144;
    float* lm1   = lm0   + 6144;
    float* f1phi = lm1   + 6144;         // 12288
    float* g1gam = f1phi + 12288;        // 12288
    float* f2    = g1gam + 12288;        // 6144
    float* g2    = f2    + 6144;
    (void)lm0; (void)lm1; (void)f2;
    // bf16 (ushort) region, 16B aligned
    unsigned short* sb = (unsigned short*)(g2 + 6144 + 32);
    unsigned short* Eh  = sb;             sb += 425984;  // 1024*416
    unsigned short* El  = sb;             sb += 425984;
    unsigned short* B1h = sb;             sb += 266240;  // 5*52*128*8
    unsigned short* B1l = sb;             sb += 266240;
    unsigned short* B2h = sb;             sb += 159744;  // 3*52*128*8
    unsigned short* B2l = sb;             sb += 159744;
    unsigned short* B3h = sb;             sb += 327680;  // 5*32*256*8
    unsigned short* B3l = sb;             sb += 327680;
    unsigned short* B4h = sb;             sb += 327680;
    unsigned short* B4l = sb;             sb += 327680;
    unsigned short* B5h = sb;             sb += 327680;
    unsigned short* B5l = sb;             sb += 327680;
    unsigned short* X3h = sb;             sb += 262144;  // 1024*256
    unsigned short* X3l = sb;             sb += 262144;
    unsigned short* X4h = sb;             sb += 262144;
    unsigned short* X4l = sb;             sb += 262144;

    // --- staging ---
    PreArgs pa;
    pa.w1 = w1; pa.w2 = w2; pa.w3 = w3; pa.w4 = w4; pa.w5 = w5;
    pa.B1h = B1h; pa.B1l = B1l; pa.B2h = B2h; pa.B2l = B2l;
    pa.B3h = B3h; pa.B3l = B3l; pa.B4h = B4h; pa.B4l = B4l;
    pa.B5h = B5h; pa.B5l = B5l;
    pa.x = x; pa.gen = gen; pa.dom = dom; pa.Eh = Eh; pa.El = El;
    pa.wf = wf; pa.wc = wc; pa.Wfc = Wfc;
    stage_kernel<<<dim3(1280, 7), 256, 0, stream>>>(pa);

    // --- convs (MFMA split-bf16, M16/N64 tile = 256 blocks each) ---
    conv1_mfma<<<dim3(64, 5), 256, 0, stream>>>(Eh, El, B1h, B1l, B2h, B2l, b1, b2,
                                                X3h, X3l, wf, bf, wc, Wfc, U);
    conv256_mfma<<<dim3(64, 4), 256, 0, stream>>>(X3h, X3l, B3h, B3l, b3, 0,
                                                  X4h, X4l, nullptr);
    conv256_mfma<<<dim3(64, 4), 256, 0, stream>>>(X4h, X4l, B4h, B4l, b4, 0,
                                                  X3h, X3l, nullptr);
    conv256_mfma<<<dim3(64, 4), 256, 0, stream>>>(X3h, X3l, B5h, B5l, b5, 1,
                                                  nullptr, nullptr, bufB);
    // xc = bufB (fp32)

    // --- attention (+ fused f0/g0) ---
    qv_v2<<<M_TOK, 128, 0, stream>>>(bufB, wq, bq, wv, bv, qb, vb);
    attn_v2<<<M_TOK, 256, 0, stream>>>(bufB, qb, vb, vv, xmask, wc, bc, xc2, f0, g0);

    // --- hops: 2 fused kernels ---
    hop1_kernel<<<128, 256, 0, stream>>>(xc2, U, f0, g0, bc, f1phi, g1gam);
    hop2_kernel<<<128, 256, 0, stream>>>(f1phi, g1gam, U, bc, (float*)d_out);
}

// Round 4
// 242.218 us; speedup vs baseline: 1.8783x; 1.0057x over previous
//
#include <hip/hip_runtime.h>
#include <math.h>

#define LSEQ 128
#define BB 8
#define M_TOK (BB*LSEQ)   // 1024

typedef __attribute__((ext_vector_type(8))) short short8;
typedef __attribute__((ext_vector_type(4))) float floatx4;

__device__ __forceinline__ unsigned short bf16_rne(float v) {
    union { float f; unsigned u; } a; a.f = v;
    return (unsigned short)((a.u + 0x7fffu + ((a.u >> 16) & 1u)) >> 16);
}
__device__ __forceinline__ float bf16_to_f(unsigned short h) {
    union { unsigned u; float f; } b; b.u = ((unsigned)h) << 16;
    return b.f;
}
__device__ __forceinline__ void split2(float v, unsigned short& h, unsigned short& l) {
    h = bf16_rne(v);
    l = bf16_rne(v - bf16_to_f(h));
}

// ---------------- staging: pack all conv weights (split bf16, MFMA B-layout),
// embedding gather+split, Wfc — one launch ----------------
struct PreArgs {
    const float *w1, *w2, *w3, *w4, *w5;
    unsigned short *B1h, *B1l, *B2h, *B2l, *B3h, *B3l, *B4h, *B4l, *B5h, *B5l;
    const int* x;
    const float* gen;
    const float* dom;
    unsigned short *Eh, *El;
    const float* wf;
    const float* wc;
    float* Wfc;
};
__global__ __launch_bounds__(256) void stage_kernel(PreArgs a) {
    int y = blockIdx.y;
    int tid = threadIdx.x;
    if (y < 3) {
        const float* w = (y == 0) ? a.w3 : (y == 1) ? a.w4 : a.w5;
        unsigned short* dh = (y == 0) ? a.B3h : (y == 1) ? a.B4h : a.B5h;
        unsigned short* dl = (y == 0) ? a.B3l : (y == 1) ? a.B4l : a.B5l;
        int idx = blockIdx.x * 256 + tid;          // < 327680 exactly
        int j = idx & 7;
        int n = (idx >> 3) & 255;
        int g = idx >> 11;
        int cg = g & 31, kk = g >> 5;
        int ci = cg * 8 + j;
        float v = w[(n * 256 + ci) * 5 + kk];
        unsigned short h, l; split2(v, h, l);
        dh[idx] = h; dl[idx] = l;
    } else if (y == 3) {
        int idx = blockIdx.x * 256 + tid;
        if (idx >= 5 * 52 * 128 * 8) return;
        int j = idx & 7;
        int n = (idx >> 3) & 127;
        int g = idx >> 10;
        int cg = g % 52, kk = g / 52;
        int ci = cg * 8 + j;
        float v = (ci < 400) ? a.w1[(n * 400 + ci) * 5 + kk] : 0.f;
        unsigned short h, l; split2(v, h, l);
        a.B1h[idx] = h; a.B1l[idx] = l;
    } else if (y == 4) {
        int idx = blockIdx.x * 256 + tid;
        if (idx >= 3 * 52 * 128 * 8) return;
        int j = idx & 7;
        int n = (idx >> 3) & 127;
        int g = idx >> 10;
        int cg = g % 52, kk = g / 52;
        int ci = cg * 8 + j;
        float v = (ci < 400) ? a.w2[(n * 400 + ci) * 3 + kk] : 0.f;
        unsigned short h, l; split2(v, h, l);
        a.B2h[idx] = h; a.B2l[idx] = l;
    } else if (y == 5) {
        int m = blockIdx.x;
        if (m >= M_TOK) return;
        int t = a.x[m];
        for (int c = tid; c < 416; c += 256) {
            float v = (c < 300) ? a.gen[t * 300 + c]
                    : (c < 400) ? a.dom[t * 100 + (c - 300)] : 0.f;
            unsigned short h, l; split2(v, h, l);
            a.Eh[m * 416 + c] = h;
            a.El[m * 416 + c] = l;
        }
    } else {
        // Wfc[r,c] = sum_n wf[r,n]*wc[n,c], r < 512
        int r = blockIdx.x;
        if (r >= 512 || tid >= 64) return;
        int l = tid;
        float p[6] = {0,0,0,0,0,0};
        const float* row = a.wf + r * 512;
        #pragma unroll
        for (int k = 0; k < 8; ++k) {
            int n = l + 64 * k;
            float v = row[n];
            #pragma unroll
            for (int c = 0; c < 6; ++c) p[c] += v * a.wc[n * 6 + c];
        }
        #pragma unroll
        for (int c = 0; c < 6; ++c)
            for (int off = 32; off >= 1; off >>= 1) p[c] += __shfl_xor(p[c], off, 64);
        if (l == 0) {
            #pragma unroll
            for (int c = 0; c < 6; ++c) a.Wfc[r * 6 + c] = p[c];
        }
    }
}

// ---------------- conv1 MFMA (+precomp2 on by==4) ----------------
__global__ __launch_bounds__(256) void conv1_mfma(
        const unsigned short* __restrict__ Eh, const unsigned short* __restrict__ El,
        const unsigned short* __restrict__ B1h, const unsigned short* __restrict__ B1l,
        const unsigned short* __restrict__ B2h, const unsigned short* __restrict__ B2l,
        const float* __restrict__ b1, const float* __restrict__ b2,
        unsigned short* __restrict__ Xoh, unsigned short* __restrict__ Xol,
        const float* __restrict__ wf, const float* __restrict__ bf,
        const float* __restrict__ wc, const float* __restrict__ Wfc,
        float* __restrict__ U) {
    __shared__ __align__(16) unsigned short xsh[20 * 424];
    __shared__ __align__(16) unsigned short xsl[20 * 424];
    int by = blockIdx.y;
    int tid = threadIdx.x;
    if (by == 4) {
        // precomp2: U[r,0:12] = row_r @ [wc | Wfc]
        if (tid >= 64) return;
        int l = tid;
        for (int i = 0; i < 9; ++i) {
            int r = blockIdx.x + 64 * i;
            if (r >= 531) break;
            const float* row = (r < 530) ? (wf + r * 512) : bf;
            float p[12];
            #pragma unroll
            for (int c = 0; c < 12; ++c) p[c] = 0.f;
            #pragma unroll
            for (int k = 0; k < 8; ++k) {
                int n = l + 64 * k;
                float v = row[n];
                #pragma unroll
                for (int c = 0; c < 6; ++c) {
                    p[c]     += v * wc[n * 6 + c];
                    p[c + 6] += v * Wfc[n * 6 + c];
                }
            }
            #pragma unroll
            for (int c = 0; c < 12; ++c)
                for (int off = 32; off >= 1; off >>= 1) p[c] += __shfl_xor(p[c], off, 64);
            if (l == 0) {
                #pragma unroll
                for (int c = 0; c < 12; ++c) U[r * 12 + c] = p[c];
            }
        }
        return;
    }
    int mt = blockIdx.x;
    int p0 = mt * 16;
    int b = p0 >> 7, l0 = p0 & 127;
    for (int i = tid; i < 2 * 1040; i += 256) {
        int sel = i >= 1040;
        int u2 = sel ? i - 1040 : i;
        int j = u2 / 52, cg = u2 % 52;
        int l = l0 - 2 + j;
        short8 v = {0,0,0,0,0,0,0,0};
        if (l >= 0 && l < 128) {
            const unsigned short* src = (sel ? El : Eh) + (b * 128 + l) * 416 + cg * 8;
            v = *(const short8*)src;
        }
        *(short8*)((sel ? xsl : xsh) + j * 424 + cg * 8) = v;
    }
    __syncthreads();
    int w = tid >> 6, lane = tid & 63;
    int m = lane & 15, q = lane >> 4;
    bool br2 = (by >= 2);
    int n0b = (by & 1) * 64;
    int nB = n0b + w * 16 + m;
    floatx4 acc0 = {0,0,0,0}, acc1 = {0,0,0,0}, acc2 = {0,0,0,0};
    if (!br2) {
        for (int kk = 0; kk < 5; ++kk) {
            const unsigned short* arh = xsh + (m + kk) * 424;
            const unsigned short* arl = xsl + (m + kk) * 424;
            #pragma unroll
            for (int u = 0; u < 13; ++u) {
                short8 ah = *(const short8*)(arh + u * 32 + q * 8);
                short8 al = *(const short8*)(arl + u * 32 + q * 8);
                int boff = (((kk * 52 + u * 4 + q) * 128) + nB) * 8;
                short8 bh = *(const short8*)(B1h + boff);
                short8 bl = *(const short8*)(B1l + boff);
                acc0 = __builtin_amdgcn_mfma_f32_16x16x32_bf16(ah, bh, acc0, 0, 0, 0);
                acc1 = __builtin_amdgcn_mfma_f32_16x16x32_bf16(ah, bl, acc1, 0, 0, 0);
                acc2 = __builtin_amdgcn_mfma_f32_16x16x32_bf16(al, bh, acc2, 0, 0, 0);
            }
        }
    } else {
        for (int kk = 0; kk < 3; ++kk) {
            const unsigned short* arh = xsh + (m + kk + 1) * 424;
            const unsigned short* arl = xsl + (m + kk + 1) * 424;
            #pragma unroll
            for (int u = 0; u < 13; ++u) {
                short8 ah = *(const short8*)(arh + u * 32 + q * 8);
                short8 al = *(const short8*)(arl + u * 32 + q * 8);
                int boff = (((kk * 52 + u * 4 + q) * 128) + nB) * 8;
                short8 bh = *(const short8*)(B2h + boff);
                short8 bl = *(const short8*)(B2l + boff);
                acc0 = __builtin_amdgcn_mfma_f32_16x16x32_bf16(ah, bh, acc0, 0, 0, 0);
                acc1 = __builtin_amdgcn_mfma_f32_16x16x32_bf16(ah, bl, acc1, 0, 0, 0);
                acc2 = __builtin_amdgcn_mfma_f32_16x16x32_bf16(al, bh, acc2, 0, 0, 0);
            }
        }
    }
    __syncthreads();
    float* fl = (float*)xsh;   // 16 x 68 tile
    #pragma unroll
    for (int reg = 0; reg < 4; ++reg)
        fl[(q * 4 + reg) * 68 + w * 16 + m] = acc0[reg] + acc1[reg] + acc2[reg];
    __syncthreads();
    int ocb = br2 ? 128 + n0b : n0b;
    const float* bias = br2 ? b2 : b1;
    #pragma unroll
    for (int i = 0; i < 4; ++i) {
        int e = tid + 256 * i;
        int mm = e >> 6, nn = e & 63;
        float val = fl[mm * 68 + nn] + bias[n0b + nn];
        val = fmaxf(val, 0.f);
        unsigned short h, l; split2(val, h, l);
        int o = (p0 + mm) * 256 + ocb + nn;
        Xoh[o] = h; Xol[o] = l;
    }
}

// ---------------- conv256 MFMA: 256->256, k=5, p=2, relu; M16/N64 tile ----------------
__global__ __launch_bounds__(256) void conv256_mfma(
        const unsigned short* __restrict__ Xih, const unsigned short* __restrict__ Xil,
        const unsigned short* __restrict__ Bh, const unsigned short* __restrict__ Bl,
        const float* __restrict__ bias, int outmode,
        unsigned short* __restrict__ Xoh, unsigned short* __restrict__ Xol,
        float* __restrict__ fout) {
    __shared__ __align__(16) unsigned short xsh[20 * 264];
    __shared__ __align__(16) unsigned short xsl[20 * 264];
    int mt = blockIdx.x;
    int p0 = mt * 16;
    int b = p0 >> 7, l0 = p0 & 127;
    int n0 = blockIdx.y * 64;
    int tid = threadIdx.x;
    for (int i = tid; i < 2 * 640; i += 256) {
        int sel = i >= 640;
        int u2 = sel ? i - 640 : i;
        int j = u2 >> 5, cg = u2 & 31;
        int l = l0 - 2 + j;
        short8 v = {0,0,0,0,0,0,0,0};
        if (l >= 0 && l < 128) {
            const unsigned short* src = (sel ? Xil : Xih) + (b * 128 + l) * 256 + cg * 8;
            v = *(const short8*)src;
        }
        *(short8*)((sel ? xsl : xsh) + j * 264 + cg * 8) = v;
    }
    __syncthreads();
    int w = tid >> 6, lane = tid & 63;
    int m = lane & 15, q = lane >> 4;
    int nB = n0 + w * 16 + m;
    floatx4 acc0 = {0,0,0,0}, acc1 = {0,0,0,0}, acc2 = {0,0,0,0};
    for (int kk = 0; kk < 5; ++kk) {
        const unsigned short* arh = xsh + (m + kk) * 264;
        const unsigned short* arl = xsl + (m + kk) * 264;
        #pragma unroll
        for (int u = 0; u < 8; ++u) {
            short8 ah = *(const short8*)(arh + u * 32 + q * 8);
            short8 al = *(const short8*)(arl + u * 32 + q * 8);
            int boff = (((kk * 32 + u * 4 + q) * 256) + nB) * 8;
            short8 bh = *(const short8*)(Bh + boff);
            short8 bl = *(const short8*)(Bl + boff);
            acc0 = __builtin_amdgcn_mfma_f32_16x16x32_bf16(ah, bh, acc0, 0, 0, 0);
            acc1 = __builtin_amdgcn_mfma_f32_16x16x32_bf16(ah, bl, acc1, 0, 0, 0);
            acc2 = __builtin_amdgcn_mfma_f32_16x16x32_bf16(al, bh, acc2, 0, 0, 0);
        }
    }
    __syncthreads();
    float* fl = (float*)xsh;   // 16 x 68 tile
    #pragma unroll
    for (int reg = 0; reg < 4; ++reg)
        fl[(q * 4 + reg) * 68 + w * 16 + m] = acc0[reg] + acc1[reg] + acc2[reg];
    __syncthreads();
    #pragma unroll
    for (int i = 0; i < 4; ++i) {
        int e = tid + 256 * i;
        int mm = e >> 6, nn = e & 63;
        float val = fl[mm * 68 + nn] + bias[n0 + nn];
        val = fmaxf(val, 0.f);
        int o = (p0 + mm) * 256 + n0 + nn;
        if (outmode == 0) {
            unsigned short h, l; split2(val, h, l);
            Xoh[o] = h; Xol[o] = l;
        } else {
            fout[o] = val;
        }
    }
}

// ---------------- q/v projection v3: W staged in LDS, 4 tokens/block ----------------
// grid: 512 blocks = (token-group 0..255) x (q/v). W traffic 104MB -> 26MB L2.
__global__ __launch_bounds__(256) void qv_v3(const float* __restrict__ xc,
        const float* __restrict__ wq, const float* __restrict__ bq,
        const float* __restrict__ wv, const float* __restrict__ bv,
        float* __restrict__ q, float* __restrict__ v) {
    __shared__ float Ws[12800];      // 256 x 50
    __shared__ float xs[4 * 257];    // 4 token rows, padded stride
    int tid = threadIdx.x;
    int bid = blockIdx.x;
    int wsel = bid & 1;
    int m0 = (bid >> 1) * 4;
    const float* Wg = wsel ? wv : wq;
    for (int i = tid; i < 12800; i += 256) Ws[i] = Wg[i];
    for (int i = tid; i < 1024; i += 256) {
        int t = i >> 8, c = i & 255;
        xs[t * 257 + c] = xc[(m0 + t) * 256 + c];
    }
    __syncthreads();
    if (tid < 200) {
        int t = tid / 50, d = tid - t * 50;
        float a = wsel ? bv[d] : bq[d];
        const float* xrow = xs + t * 257;
        #pragma unroll 8
        for (int c = 0; c < 256; ++c) a += xrow[c] * Ws[c * 50 + d];
        (wsel ? v : q)[(m0 + t) * 50 + d] = a;
    }
}

// ---------------- attention v2: 256 threads/row, LDS-staged V, fast tanh ----------------
__global__ __launch_bounds__(256) void attn_v2(const float* __restrict__ xc,
        const float* __restrict__ q, const float* __restrict__ v,
        const float* __restrict__ vv, const float* __restrict__ xmask,
        const float* __restrict__ wc, const float* __restrict__ bc,
        float* __restrict__ xc2, float* __restrict__ f0, float* __restrict__ g0) {
    __shared__ float vs[128 * 50];   // 25.6 KB
    __shared__ float spart[128], aarr[128], xrow[256], qrow[52], vvs[52], red[4];
    int bi = blockIdx.x;             // b*L + i
    int b = bi >> 7;
    int tid = threadIdx.x;
    for (int idx = tid; idx < 128 * 50; idx += 256) vs[idx] = v[b * 6400 + idx];
    if (tid < 50) { qrow[tid] = q[bi * 50 + tid]; vvs[tid] = vv[tid]; }
    __syncthreads();
    int j = tid & 127, half = tid >> 7;
    int d0 = half * 25;
    const float* vj = vs + j * 50 + d0;
    float s = 0.f;
    #pragma unroll
    for (int d = 0; d < 25; ++d) {
        float x = qrow[d0 + d] + vj[d];
        float e = __expf(2.f * x);               // tanh(x) = 1 - 2/(e^(2x)+1)
        s += (1.f - 2.f / (e + 1.f)) * vvs[d0 + d];
    }
    if (half) spart[j] = s;
    __syncthreads();
    float stot = 0.f;
    if (!half) {
        stot = s + spart[j];
        if (xmask[b * LSEQ + j] == 0.f) stot = -1e9f;
    }
    if (tid < 128) {
        float m = stot;
        #pragma unroll
        for (int off = 32; off >= 1; off >>= 1) m = fmaxf(m, __shfl_xor(m, off, 64));
        if ((tid & 63) == 0) red[tid >> 6] = m;
    }
    __syncthreads();
    float mx = fmaxf(red[0], red[1]);
    float e = 0.f;
    if (tid < 128) {
        e = __expf(stot - mx);
        float su = e;
        #pragma unroll
        for (int off = 32; off >= 1; off >>= 1) su += __shfl_xor(su, off, 64);
        if ((tid & 63) == 0) red[2 + (tid >> 6)] = su;
    }
    __syncthreads();
    float denom = red[2] + red[3];
    if (tid < 128) aarr[j] = e / denom;
    __syncthreads();
    float maskI = xmask[bi];
    const float* xcb = xc + b * LSEQ * 256;
    float acc = 0.f;
    #pragma unroll 8
    for (int jj = 0; jj < 128; ++jj) acc += aarr[jj] * xcb[jj * 256 + tid];
    float val = xc[bi * 256 + tid] + acc * maskI;
    xc2[bi * 256 + tid] = val;
    xrow[tid] = val;
    __syncthreads();
    int grp = tid >> 4, l16 = tid & 15;
    if (grp < 12) {
        int c = grp % 6, gsel = grp / 6;
        const float* wcc = wc + gsel * 256 * 6 + c;
        float a = 0.f;
        #pragma unroll
        for (int ch = l16; ch < 256; ch += 16) a += xrow[ch] * wcc[ch * 6];
        #pragma unroll
        for (int off = 8; off >= 1; off >>= 1) a += __shfl_down(a, off, 16);
        if (l16 == 0) {
            if (gsel == 0) f0[bi * 6 + c] = a + bc[c];
            else           g0[bi * 6 + c] = a;
        }
    }
}

// ---------------- lm scan (strided input): parallel prefix/suffix max ----------------
__global__ __launch_bounds__(128) void lm_scan_v3(const float* __restrict__ f,
        const float* __restrict__ g, int stride, float* __restrict__ lm) {
    __shared__ float sf[128], sg[128];
    int bc = blockIdx.x;          // b*6 + c
    int b = bc / 6, c = bc - b * 6;
    int p = threadIdx.x;
    float fv = f[(b * LSEQ + p) * stride + c];
    float gv = g[(b * LSEQ + p) * stride + c];
    sf[p] = fv; sg[p] = gv;
    __syncthreads();
    float pf = fv, sgx = gv;
    #pragma unroll
    for (int off = 1; off < 128; off <<= 1) {
        float a = (p >= off) ? sf[p - off] : -INFINITY;
        float d = (p + off < 128) ? sg[p + off] : -INFINITY;
        __syncthreads();
        pf = fmaxf(pf, a); sgx = fmaxf(sgx, d);
        sf[p] = pf; sg[p] = sgx;
        __syncthreads();
    }
    float M1 = pf + gv;
    if (p < LSEQ - 1) M1 = fmaxf(M1, 0.f);
    float M2 = fv + sgx;
    if (p > 0) M2 = fmaxf(M2, 0.f);
    lm[(b * LSEQ + p) * 6 + c] = fmaxf(M1, M2);
}

// ---------------- hop fold: [f1,phi1] / [g1,gam1] per token (U from global/L2) ----------------
__global__ __launch_bounds__(64) void hopfold_kernel(const float* __restrict__ xc2,
        const float* __restrict__ U, const float* __restrict__ lm0,
        const float* __restrict__ f0, const float* __restrict__ g0,
        const float* __restrict__ bc,
        float* __restrict__ outF, float* __restrict__ outG) {
    int m = blockIdx.x;
    int y = blockIdx.y;
    int tid = threadIdx.x;
    const float* Urows = U + (y ? 256 : 0) * 12;
    float p[12];
    #pragma unroll
    for (int c = 0; c < 12; ++c) p[c] = 0.f;
    for (int k = tid; k < 256; k += 64) {
        float a = xc2[m * 256 + k];
        const float* ur = Urows + k * 12;
        #pragma unroll
        for (int c = 0; c < 12; ++c) p[c] += a * ur[c];
    }
    #pragma unroll
    for (int c = 0; c < 12; ++c)
        for (int off = 32; off >= 1; off >>= 1) p[c] += __shfl_xor(p[c], off, 64);
    if (tid == 0) {
        const float* Bb = U + (y ? 518 : 512) * 12;
        const float* Db = U + 524 * 12;
        const float* fg = y ? g0 : f0;
        float* out = y ? outG : outF;
        float lmv[6], fgv[6];
        #pragma unroll
        for (int j = 0; j < 6; ++j) { lmv[j] = lm0[m * 6 + j]; fgv[j] = fg[m * 6 + j]; }
        #pragma unroll
        for (int c = 0; c < 12; ++c) {
            float s = p[c];
            #pragma unroll
            for (int j = 0; j < 6; ++j) s += lmv[j] * Bb[j * 12 + c] + fgv[j] * Db[j * 12 + c];
            if (!y) { s += U[530 * 12 + c]; if (c < 6) s += bc[c]; }
            out[m * 12 + c] = s;
        }
    }
}

// ---------------- f2/g2 finalize ----------------
__global__ __launch_bounds__(128) void f2g2_kernel(const float* __restrict__ f1phi,
        const float* __restrict__ g1gam, const float* __restrict__ lm1,
        const float* __restrict__ U, const float* __restrict__ bc,
        float* __restrict__ f2, float* __restrict__ g2) {
    __shared__ float Us[19 * 12], bcs[6];
    int tid = threadIdx.x;
    for (int i = tid; i < 19 * 12; i += 128) Us[i] = U[512 * 12 + i];
    if (tid < 6) bcs[tid] = bc[tid];
    __syncthreads();
    int m = blockIdx.x * 128 + tid;
    float lmv[6], f1v[6], g1v[6];
    #pragma unroll
    for (int j = 0; j < 6; ++j) {
        lmv[j] = lm1[m * 6 + j];
        f1v[j] = f1phi[m * 12 + j];
        g1v[j] = g1gam[m * 12 + j];
    }
    #pragma unroll
    for (int c = 0; c < 6; ++c) {
        float sf = f1phi[m * 12 + 6 + c] + Us[18 * 12 + c] + bcs[c];
        float sg = g1gam[m * 12 + 6 + c];
        #pragma unroll
        for (int j = 0; j < 6; ++j) {
            sf += lmv[j] * Us[j * 12 + c]       + f1v[j] * Us[(12 + j) * 12 + c];
            sg += lmv[j] * Us[(6 + j) * 12 + c] + g1v[j] * Us[(12 + j) * 12 + c];
        }
        f2[m * 6 + c] = sf;
        g2[m * 6 + c] = sg;
    }
}

// ---------------- final separable write ----------------
__global__ __launch_bounds__(256) void writeout_kernel(const float* __restrict__ f2,
        const float* __restrict__ g2, float* __restrict__ out) {
    int idx = blockIdx.x * 256 + threadIdx.x;   // < 8*128*128*6
    int c = idx % 6;
    int r = idx / 6;
    int j = r & 127;
    int bi = r >> 7;
    int b = bi >> 7;
    out[idx] = f2[bi * 6 + c] + g2[(b * LSEQ + j) * 6 + c];
}

extern "C" void kernel_launch(void* const* d_in, const int* in_sizes, int n_in,
                              void* d_out, int out_size, void* d_ws, size_t ws_size,
                              hipStream_t stream) {
    const int*   x     = (const int*)d_in[0];
    const float* xmask = (const float*)d_in[2];
    const float* gen   = (const float*)d_in[3];
    const float* dom   = (const float*)d_in[4];
    const float* w1    = (const float*)d_in[5];
    const float* b1    = (const float*)d_in[6];
    const float* w2    = (const float*)d_in[7];
    const float* b2    = (const float*)d_in[8];
    const float* w3    = (const float*)d_in[9];
    const float* b3    = (const float*)d_in[10];
    const float* w4    = (const float*)d_in[11];
    const float* b4    = (const float*)d_in[12];
    const float* w5    = (const float*)d_in[13];
    const float* b5    = (const float*)d_in[14];
    const float* wq    = (const float*)d_in[15];
    const float* bq    = (const float*)d_in[16];
    const float* wv    = (const float*)d_in[17];
    const float* bv    = (const float*)d_in[18];
    const float* vv    = (const float*)d_in[19];
    const float* wf    = (const float*)d_in[20];
    const float* bf    = (const float*)d_in[21];
    const float* wc    = (const float*)d_in[22];
    const float* bc    = (const float*)d_in[23];

    // fp32 region
    float* fb = (float*)d_ws;
    float* bufB  = fb;                   // 262144  (xc, conv5 out)
    float* xc2   = bufB  + 262144;       // 262144
    float* qb    = xc2   + 262144;       // 51200
    float* vb    = qb    + 51200;        // 51200
    float* Wfc   = vb    + 51200;        // 3072
    float* U     = Wfc   + 3072;         // 6376 (pad)
    float* f0    = U     + 6376;         // 6144
    float* g0    = f0    + 6144;
    float* lm0   = g0    + 6144;
    float* lm1   = lm0   + 6144;
    float* f1phi = lm1   + 6144;         // 12288
    float* g1gam = f1phi + 12288;        // 12288
    float* f2    = g1gam + 12288;        // 6144
    float* g2    = f2    + 6144;
    // bf16 (ushort) region, 16B aligned
    unsigned short* sb = (unsigned short*)(g2 + 6144 + 32);
    unsigned short* Eh  = sb;             sb += 425984;  // 1024*416
    unsigned short* El  = sb;             sb += 425984;
    unsigned short* B1h = sb;             sb += 266240;  // 5*52*128*8
    unsigned short* B1l = sb;             sb += 266240;
    unsigned short* B2h = sb;             sb += 159744;  // 3*52*128*8
    unsigned short* B2l = sb;             sb += 159744;
    unsigned short* B3h = sb;             sb += 327680;  // 5*32*256*8
    unsigned short* B3l = sb;             sb += 327680;
    unsigned short* B4h = sb;             sb += 327680;
    unsigned short* B4l = sb;             sb += 327680;
    unsigned short* B5h = sb;             sb += 327680;
    unsigned short* B5l = sb;             sb += 327680;
    unsigned short* X3h = sb;             sb += 262144;  // 1024*256
    unsigned short* X3l = sb;             sb += 262144;
    unsigned short* X4h = sb;             sb += 262144;
    unsigned short* X4l = sb;             sb += 262144;

    // --- staging: weight packs (split bf16) + embedding + Wfc ---
    PreArgs pa;
    pa.w1 = w1; pa.w2 = w2; pa.w3 = w3; pa.w4 = w4; pa.w5 = w5;
    pa.B1h = B1h; pa.B1l = B1l; pa.B2h = B2h; pa.B2l = B2l;
    pa.B3h = B3h; pa.B3l = B3l; pa.B4h = B4h; pa.B4l = B4l;
    pa.B5h = B5h; pa.B5l = B5l;
    pa.x = x; pa.gen = gen; pa.dom = dom; pa.Eh = Eh; pa.El = El;
    pa.wf = wf; pa.wc = wc; pa.Wfc = Wfc;
    stage_kernel<<<dim3(1280, 7), 256, 0, stream>>>(pa);

    // --- convs (MFMA split-bf16) ---
    conv1_mfma<<<dim3(64, 5), 256, 0, stream>>>(Eh, El, B1h, B1l, B2h, B2l, b1, b2,
                                                X3h, X3l, wf, bf, wc, Wfc, U);
    conv256_mfma<<<dim3(64, 4), 256, 0, stream>>>(X3h, X3l, B3h, B3l, b3, 0,
                                                  X4h, X4l, nullptr);
    conv256_mfma<<<dim3(64, 4), 256, 0, stream>>>(X4h, X4l, B4h, B4l, b4, 0,
                                                  X3h, X3l, nullptr);
    conv256_mfma<<<dim3(64, 4), 256, 0, stream>>>(X3h, X3l, B5h, B5l, b5, 1,
                                                  nullptr, nullptr, bufB);
    // xc = bufB (fp32)

    // --- attention (+ fused f0/g0) ---
    qv_v3<<<512, 256, 0, stream>>>(bufB, wq, bq, wv, bv, qb, vb);
    attn_v2<<<M_TOK, 256, 0, stream>>>(bufB, qb, vb, vv, xmask, wc, bc, xc2, f0, g0);

    // --- hops (fully folded, wide grids) ---
    lm_scan_v3<<<48, 128, 0, stream>>>(f0, g0, 6, lm0);
    hopfold_kernel<<<dim3(M_TOK, 2), 64, 0, stream>>>(xc2, U, lm0, f0, g0, bc, f1phi, g1gam);
    lm_scan_v3<<<48, 128, 0, stream>>>(f1phi, g1gam, 12, lm1);
    f2g2_kernel<<<8, 128, 0, stream>>>(f1phi, g1gam, lm1, U, bc, f2, g2);

    // --- out[b,i,j,c] = f2[b,i,c] + g2[b,j,c] ---
    writeout_kernel<<<(BB*LSEQ*LSEQ*6)/256, 256, 0, stream>>>(f2, g2, (float*)d_out);
}